// Round 1
// baseline (257.136 us; speedup 1.0000x reference)
//
#include <hip/hip_runtime.h>
#include <hip/hip_bf16.h>

// out[v,g,u,d] = W[GE[v,g] % 3, d] + b[d], out shape [V=512, G=4, V=512, D=64] fp32.
// Pure write-BW bound: 256 MiB of stores, ~8 KB of reads.
// One block per (v,g): computes its 64-float row once, streams V*D floats.

#define V 512
#define G 4
#define D 64
#define D4 (D / 4)  // 16 float4 per row

__global__ __launch_bounds__(256) void gembed_kernel(
    const int* __restrict__ GE,      // [V*G] int32, values in [0,3)
    const float* __restrict__ W,     // [3, D]
    const float* __restrict__ b,     // [D]
    float* __restrict__ out)         // [V*G*V*D]
{
    const int bid = blockIdx.x;          // (v*G + g) in [0, V*G)
    const int tid = threadIdx.x;         // 0..255
    const int d4  = tid & (D4 - 1);      // which float4 within the D row
    const int u0  = tid >> 4;            // starting u-row (0..15)

    int e = GE[bid];
    e = ((e % 3) + 3) % 3;               // safety; values are already 0..2

    const float4* __restrict__ W4 = (const float4*)W;  // [3 * D4]
    const float4* __restrict__ b4 = (const float4*)b;  // [D4]

    float4 w = W4[e * D4 + d4];
    float4 bb = b4[d4];
    float4 val;
    val.x = w.x + bb.x;
    val.y = w.y + bb.y;
    val.z = w.z + bb.z;
    val.w = w.w + bb.w;

    // Block writes V rows of D floats = V * D4 float4s, contiguous.
    float4* __restrict__ out4 = (float4*)out + (size_t)bid * (V * D4);

    // 256 threads cover 16 u-rows per sweep (16 float4 x 16 rows); 32 sweeps.
    #pragma unroll 8
    for (int u = u0; u < V; u += 16) {
        out4[u * D4 + d4] = val;
    }
}

extern "C" void kernel_launch(void* const* d_in, const int* in_sizes, int n_in,
                              void* d_out, int out_size, void* d_ws, size_t ws_size,
                              hipStream_t stream) {
    const int*   GE = (const int*)d_in[0];
    const float* W  = (const float*)d_in[1];
    const float* b  = (const float*)d_in[2];
    float* out = (float*)d_out;

    gembed_kernel<<<V * G, 256, 0, stream>>>(GE, W, b, out);
}